// Round 14
// baseline (585.438 us; speedup 1.0000x reference)
//
#include <hip/hip_runtime.h>
#include <math.h>

#define NSEQ 256
#define HD 128
#define FD 512
#define NHD 8
#define LNEPS 1e-5f

typedef __attribute__((ext_vector_type(8))) short bf16x8;
typedef __attribute__((ext_vector_type(4))) float f32x4;

__device__ __forceinline__ unsigned short f2bf(float x) {
  union { float f; unsigned int u; } v; v.f = x;
  unsigned int r = v.u + 0x7fffu + ((v.u >> 16) & 1u);
  return (unsigned short)(r >> 16);
}

__device__ __forceinline__ float bf2f(unsigned short u) {
  union { float f; unsigned int v; } cv; cv.v = ((unsigned int)u) << 16;
  return cv.f;
}

// ---------------- K0: prep weights ---------------------------------------------
// x-path: [n][k]. e-path: FRAGMENT-MAJOR (each 16x32 B-tile = 64 consecutive
// 16B lane-chunks; lane l reads chunk l — fully coalesced). R11/R12-proven.
__global__ void prep_weights(
    const float* __restrict__ W1x, const float* __restrict__ W2x,
    const float* __restrict__ W1e, const float* __restrict__ W2e,
    unsigned short* __restrict__ W1Tx, unsigned short* __restrict__ W2Tx,
    unsigned short* __restrict__ W1Fe, unsigned short* __restrict__ W2Fe) {
  int t = blockIdx.x * 256 + threadIdx.x;
  int tot = gridDim.x * 256;
  for (int idx = t; idx < FD * HD; idx += tot) {       // W1: k<128, n<512
    int n = idx >> 7, k = idx & (HD - 1);
    W1Tx[idx] = f2bf(W1x[k * FD + n]);
    float ve = W1e[k * FD + n];
    int dst = ((((n >> 4) * 4 + (k >> 5)) * 64) + ((k >> 3) & 3) * 16 + (n & 15)) * 8 + (k & 7);
    W1Fe[dst] = f2bf(ve);
  }
  for (int idx = t; idx < HD * FD; idx += tot) {       // W2: k<512, n<128
    int n = idx >> 9, k = idx & (FD - 1);
    W2Tx[idx] = f2bf(W2x[k * HD + n]);
    float ve = W2e[k * HD + n];
    int dst = ((((n >> 4) * 16 + (k >> 5)) * 64) + ((k >> 3) & 3) * 16 + (n & 15)) * 8 + (k & 7);
    W2Fe[dst] = f2bf(ve);
  }
}

// ---------------- K1: Q,K projections (V reuses K per the reference bug) --------
__global__ __launch_bounds__(128) void qk_proj(const float* __restrict__ x,
    const float* __restrict__ Wq, const float* __restrict__ bq,
    const float* __restrict__ Wk, const float* __restrict__ bk,
    float* __restrict__ Qs, float* __restrict__ Kp) {
  int row = blockIdx.x;         // b*N+i
  int c = threadIdx.x;
  __shared__ float xl[HD];
  xl[c] = x[row * HD + c];
  __syncthreads();
  float aq = bq[c], ak = bk[c];
  #pragma unroll 8
  for (int k = 0; k < HD; ++k) {
    float xv = xl[k];
    aq = fmaf(xv, Wq[k * HD + c], aq);
    ak = fmaf(xv, Wk[k * HD + c], ak);
  }
  Qs[row * HD + c] = aq * 0.25f;   // fold scale = 1/sqrt(16)
  Kp[row * HD + c] = ak;
}

// ---------------- K2: fused edge attention, bf16 MFMA (R8-proven) --------------
__global__ __launch_bounds__(256) void edge_attn(
    const float* __restrict__ e,
    const float* __restrict__ We, const float* __restrict__ be,
    const float* __restrict__ Woe, const float* __restrict__ boe,
    const float* __restrict__ Qs, const float* __restrict__ Kp,
    const float* __restrict__ g1e, const float* __restrict__ b1e,
    float* __restrict__ Sout, float* __restrict__ e1out) {
  const int gid = blockIdx.x;
  const int jt = gid & 3, i = (gid >> 2) & (NSEQ - 1), b = gid >> 10;
  const int j0 = jt * 64;
  const int t = threadIdx.x;
  const int w = t >> 6, l = t & 63;
  const int wr = w >> 1, wc = w & 1;
  const int l15 = l & 15, lg = l >> 4;

  __shared__ unsigned short eL[64 * 128];   // e tile bf16 swizzled; later holds P
  __shared__ unsigned short kL[64 * 136];   // K tile bf16, padded (no swizzle)
  __shared__ float qL[HD], beL[HD], boeL[HD], gL[HD], bbL[HD];
  __shared__ float redS[64][2], redQ[64][2];

  if (t < HD) {
    qL[t]   = Qs[(b * NSEQ + i) * HD + t];
    beL[t]  = be[t];
    boeL[t] = boe[t];
    gL[t]   = g1e[t];
    bbL[t]  = b1e[t];
  }
  const int ebase = ((b * NSEQ + i) * NSEQ + j0) * HD;
  for (int v = t; v < 64 * 16; v += 256) {
    int r = v >> 4, c8 = (v & 15) << 3;
    const float* se = &e[ebase + r * HD + c8];
    float4 e0 = *(const float4*)se;
    float4 e1v = *(const float4*)(se + 4);
    union { bf16x8 v8; unsigned short u[8]; } pk;
    pk.u[0] = f2bf(e0.x); pk.u[1] = f2bf(e0.y); pk.u[2] = f2bf(e0.z); pk.u[3] = f2bf(e0.w);
    pk.u[4] = f2bf(e1v.x); pk.u[5] = f2bf(e1v.y); pk.u[6] = f2bf(e1v.z); pk.u[7] = f2bf(e1v.w);
    *(bf16x8*)&eL[r * HD + (c8 ^ ((r & 7) << 3))] = pk.v8;
    const float* sk = &Kp[(b * NSEQ + j0 + r) * HD + c8];
    float4 k0 = *(const float4*)sk;
    float4 k1 = *(const float4*)(sk + 4);
    pk.u[0] = f2bf(k0.x); pk.u[1] = f2bf(k0.y); pk.u[2] = f2bf(k0.z); pk.u[3] = f2bf(k0.w);
    pk.u[4] = f2bf(k1.x); pk.u[5] = f2bf(k1.y); pk.u[6] = f2bf(k1.z); pk.u[7] = f2bf(k1.w);
    *(bf16x8*)&kL[r * 136 + c8] = pk.v8;
  }
  __syncthreads();

  // ---- GEMM1: Ee = e @ We + be ----
  f32x4 acc1[2][4];
  #pragma unroll
  for (int tm = 0; tm < 2; ++tm)
    #pragma unroll
    for (int tn = 0; tn < 4; ++tn) {
      float bv = beL[wc * 64 + tn * 16 + l15];
      acc1[tm][tn] = (f32x4){bv, bv, bv, bv};
    }
  #pragma unroll
  for (int ks = 0; ks < 4; ++ks) {
    bf16x8 af[2], bfr[4];
    #pragma unroll
    for (int tm = 0; tm < 2; ++tm) {
      int mrow = wr * 32 + tm * 16 + l15;
      af[tm] = *(const bf16x8*)&eL[mrow * HD + ((ks * 32 + lg * 8) ^ ((mrow & 7) << 3))];
    }
    #pragma unroll
    for (int tn = 0; tn < 4; ++tn) {
      int n = wc * 64 + tn * 16 + l15;
      const float* wp = &We[(ks * 32 + lg * 8) * HD + n];
      union { bf16x8 v8; unsigned short u[8]; } pk;
      #pragma unroll
      for (int ii = 0; ii < 8; ++ii) pk.u[ii] = f2bf(wp[ii * HD]);
      bfr[tn] = pk.v8;
    }
    #pragma unroll
    for (int tm = 0; tm < 2; ++tm)
      #pragma unroll
      for (int tn = 0; tn < 4; ++tn)
        acc1[tm][tn] = __builtin_amdgcn_mfma_f32_16x16x32_bf16(af[tm], bfr[tn], acc1[tm][tn], 0, 0, 0);
  }

  // ---- P = Ee * q * k; head-sums -> S ----
  #pragma unroll
  for (int tm = 0; tm < 2; ++tm)
    #pragma unroll
    for (int tn = 0; tn < 4; ++tn) {
      int c = wc * 64 + tn * 16 + l15;
      float qv = qL[c];
      f32x4 p;
      #pragma unroll
      for (int ii = 0; ii < 4; ++ii) {
        int r = wr * 32 + tm * 16 + lg * 4 + ii;
        p[ii] = acc1[tm][tn][ii] * qv * bf2f(kL[r * 136 + c]);
      }
      acc1[tm][tn] = p;
      float h0 = p[0], h1 = p[1], h2 = p[2], h3 = p[3];
      #pragma unroll
      for (int off = 1; off < 16; off <<= 1) {
        h0 += __shfl_xor(h0, off); h1 += __shfl_xor(h1, off);
        h2 += __shfl_xor(h2, off); h3 += __shfl_xor(h3, off);
      }
      if (l15 < 4) {
        float val = l15 == 0 ? h0 : l15 == 1 ? h1 : l15 == 2 ? h2 : h3;
        int r = wr * 32 + tm * 16 + lg * 4 + l15;
        Sout[((b * NHD + (wc * 4 + tn)) * NSEQ + i) * NSEQ + j0 + r] = val;
      }
    }
  __syncthreads();

  // ---- store P (bf16) into eL region ----
  #pragma unroll
  for (int tm = 0; tm < 2; ++tm)
    #pragma unroll
    for (int tn = 0; tn < 4; ++tn) {
      int c = wc * 64 + tn * 16 + l15;
      #pragma unroll
      for (int ii = 0; ii < 4; ++ii) {
        int r = wr * 32 + tm * 16 + lg * 4 + ii;
        eL[r * HD + (c ^ ((r & 7) << 3))] = f2bf(acc1[tm][tn][ii]);
      }
    }
  __syncthreads();

  // ---- GEMM2: e_attn = P @ Woe + boe ----
  f32x4 acc2[2][4];
  #pragma unroll
  for (int tm = 0; tm < 2; ++tm)
    #pragma unroll
    for (int tn = 0; tn < 4; ++tn) {
      float bv = boeL[wc * 64 + tn * 16 + l15];
      acc2[tm][tn] = (f32x4){bv, bv, bv, bv};
    }
  #pragma unroll
  for (int ks = 0; ks < 4; ++ks) {
    bf16x8 af[2], bfr[4];
    #pragma unroll
    for (int tm = 0; tm < 2; ++tm) {
      int mrow = wr * 32 + tm * 16 + l15;
      af[tm] = *(const bf16x8*)&eL[mrow * HD + ((ks * 32 + lg * 8) ^ ((mrow & 7) << 3))];
    }
    #pragma unroll
    for (int tn = 0; tn < 4; ++tn) {
      int n = wc * 64 + tn * 16 + l15;
      const float* wp = &Woe[(ks * 32 + lg * 8) * HD + n];
      union { bf16x8 v8; unsigned short u[8]; } pk;
      #pragma unroll
      for (int ii = 0; ii < 8; ++ii) pk.u[ii] = f2bf(wp[ii * HD]);
      bfr[tn] = pk.v8;
    }
    #pragma unroll
    for (int tm = 0; tm < 2; ++tm)
      #pragma unroll
      for (int tn = 0; tn < 4; ++tn)
        acc2[tm][tn] = __builtin_amdgcn_mfma_f32_16x16x32_bf16(af[tm], bfr[tn], acc2[tm][tn], 0, 0, 0);
  }

  // ---- + e residual; LN partials via shfl ----
  #pragma unroll
  for (int tm = 0; tm < 2; ++tm) {
    #pragma unroll
    for (int tn = 0; tn < 4; ++tn) {
      int c = wc * 64 + tn * 16 + l15;
      #pragma unroll
      for (int ii = 0; ii < 4; ++ii) {
        int r = wr * 32 + tm * 16 + lg * 4 + ii;
        acc2[tm][tn][ii] += e[ebase + r * HD + c];
      }
    }
    #pragma unroll
    for (int ii = 0; ii < 4; ++ii) {
      float s  = acc2[tm][0][ii] + acc2[tm][1][ii] + acc2[tm][2][ii] + acc2[tm][3][ii];
      float sq = acc2[tm][0][ii] * acc2[tm][0][ii] + acc2[tm][1][ii] * acc2[tm][1][ii]
               + acc2[tm][2][ii] * acc2[tm][2][ii] + acc2[tm][3][ii] * acc2[tm][3][ii];
      #pragma unroll
      for (int off = 1; off < 16; off <<= 1) {
        s += __shfl_xor(s, off); sq += __shfl_xor(sq, off);
      }
      if (l15 == 0) {
        int r = wr * 32 + tm * 16 + lg * 4 + ii;
        redS[r][wc] = s; redQ[r][wc] = sq;
      }
    }
  }
  __syncthreads();

  // ---- LN + write e1 ----
  #pragma unroll
  for (int tm = 0; tm < 2; ++tm) {
    float mrow[4], rsrow[4];
    #pragma unroll
    for (int ii = 0; ii < 4; ++ii) {
      int r = wr * 32 + tm * 16 + lg * 4 + ii;
      float s = redS[r][0] + redS[r][1];
      float sq = redQ[r][0] + redQ[r][1];
      float m = s * (1.f / HD);
      float var = sq * (1.f / HD) - m * m;
      mrow[ii] = m; rsrow[ii] = rsqrtf(var + LNEPS);
    }
    #pragma unroll
    for (int tn = 0; tn < 4; ++tn) {
      int c = wc * 64 + tn * 16 + l15;
      float gv = gL[c], bv = bbL[c];
      #pragma unroll
      for (int ii = 0; ii < 4; ++ii) {
        int r = wr * 32 + tm * 16 + lg * 4 + ii;
        e1out[ebase + r * HD + c] = (acc2[tm][tn][ii] - mrow[ii]) * rsrow[ii] * gv + bv;
      }
    }
  }
}

// ---------------- K3: softmax over j, IN PLACE on S ----------------------------
__global__ __launch_bounds__(256) void softmax_k(float* __restrict__ S,
    const float* __restrict__ mask) {
  int row = blockIdx.x;               // (b*8+h)*256+i
  int t = threadIdx.x;
  int idx = row * NSEQ + t;
  float v = S[idx] + mask[idx];
  float m = v;
  #pragma unroll
  for (int off = 1; off < 64; off <<= 1) m = fmaxf(m, __shfl_xor(m, off));
  __shared__ float wbuf[8];
  if ((t & 63) == 0) wbuf[t >> 6] = m;
  __syncthreads();
  m = fmaxf(fmaxf(wbuf[0], wbuf[1]), fmaxf(wbuf[2], wbuf[3]));
  float ex = __expf(v - m);
  float s = ex;
  #pragma unroll
  for (int off = 1; off < 64; off <<= 1) s += __shfl_xor(s, off);
  __syncthreads();
  if ((t & 63) == 0) wbuf[4 + (t >> 6)] = s;
  __syncthreads();
  s = wbuf[4] + wbuf[5] + wbuf[6] + wbuf[7];
  S[idx] = ex / s;   // safe: all reads of S complete before first barrier
}

// ---------------- K4: x attention + LN1 -> x1 ----------------------------------
__global__ __launch_bounds__(128) void x_attn_ln(
    const float* __restrict__ x, const float* __restrict__ scores,
    const float* __restrict__ Kp,
    const float* __restrict__ Woh, const float* __restrict__ boh,
    const float* __restrict__ g1x, const float* __restrict__ b1x,
    float* __restrict__ x1out) {
  int bi = blockIdx.x; int b = bi >> 8; int i = bi & 255;
  int c = threadIdx.x;
  __shared__ float sL[NHD * NSEQ];
  __shared__ float attL[HD];
  __shared__ float rbuf[4];

  for (int v = c; v < NHD * NSEQ; v += 128) {
    int h = v >> 8, j = v & 255;
    sL[v] = scores[((b * NHD + h) * NSEQ + i) * NSEQ + j];
  }
  __syncthreads();
  int h = c >> 4;
  float att = 0.f;
  for (int j = 0; j < NSEQ; ++j)
    att = fmaf(sL[h * NSEQ + j], Kp[(b * NSEQ + j) * HD + c], att);   // V = K
  attL[c] = att;
  __syncthreads();
  float o = boh[c];
  for (int k = 0; k < HD; ++k) o = fmaf(attL[k], Woh[k * HD + c], o);
  o += x[bi * HD + c];
  float s = o, s2 = o * o;
  #pragma unroll
  for (int off = 1; off < 64; off <<= 1) { s += __shfl_xor(s, off); s2 += __shfl_xor(s2, off); }
  if ((c & 63) == 0) { rbuf[(c >> 6) * 2] = s; rbuf[(c >> 6) * 2 + 1] = s2; }
  __syncthreads();
  s = rbuf[0] + rbuf[2]; s2 = rbuf[1] + rbuf[3];
  float m = s * (1.f / HD);
  float var = s2 * (1.f / HD) - m * m;
  x1out[bi * HD + c] = (o - m) * rsqrtf(var + LNEPS) * g1x[c] + b1x[c];
}

// ---------------- K5: x-FFN, bf16 MFMA, [n][k] ws weights (R4-proven) ----------
__global__ __launch_bounds__(256) void ffn_mfma(
    const float* in1,
    const unsigned short* __restrict__ W1T, const float* __restrict__ b1,
    const unsigned short* __restrict__ W2T, const float* __restrict__ b2,
    const float* __restrict__ g, const float* __restrict__ bb,
    float* out2) {
  const int row0 = blockIdx.x * 64;
  const int t = threadIdx.x;
  const int w = t >> 6, l = t & 63;
  const int wr = w >> 1, wc = w & 1;
  const int l15 = l & 15, lg = l >> 4;

  __shared__ __align__(16) char smem[34816];
  unsigned short* aL = (unsigned short*)smem;
  unsigned short* hL = (unsigned short*)(smem + 16384);
  float* b1L = (float*)(smem + 32768);
  float* epi = (float*)smem;

  for (int v = t; v < 64 * 16; v += 256) {
    int r = v >> 4, c8 = (v & 15) << 3;
    const float* src = &in1[(row0 + r) * HD + c8];
    float4 f0 = *(const float4*)src;
    float4 f1 = *(const float4*)(src + 4);
    union { bf16x8 v8; unsigned short u[8]; } pk;
    pk.u[0] = f2bf(f0.x); pk.u[1] = f2bf(f0.y); pk.u[2] = f2bf(f0.z); pk.u[3] = f2bf(f0.w);
    pk.u[4] = f2bf(f1.x); pk.u[5] = f2bf(f1.y); pk.u[6] = f2bf(f1.z); pk.u[7] = f2bf(f1.w);
    *(bf16x8*)&aL[r * HD + (c8 ^ ((r & 7) << 3))] = pk.v8;
  }
  for (int v = t; v < FD; v += 256) b1L[v] = b1[v];
  __syncthreads();

  f32x4 acc2[2][4];
  #pragma unroll
  for (int tm = 0; tm < 2; ++tm)
    #pragma unroll
    for (int tn = 0; tn < 4; ++tn) acc2[tm][tn] = (f32x4){0.f, 0.f, 0.f, 0.f};

  for (int fc = 0; fc < 4; ++fc) {
    f32x4 acc1[2][4];
    #pragma unroll
    for (int tm = 0; tm < 2; ++tm)
      #pragma unroll
      for (int tn = 0; tn < 4; ++tn) acc1[tm][tn] = (f32x4){0.f, 0.f, 0.f, 0.f};
    #pragma unroll
    for (int ks = 0; ks < 4; ++ks) {
      bf16x8 af[2], bfr[4];
      #pragma unroll
      for (int tm = 0; tm < 2; ++tm) {
        int mrow = wr * 32 + tm * 16 + l15;
        af[tm] = *(const bf16x8*)&aL[mrow * HD + ((ks * 32 + lg * 8) ^ ((mrow & 7) << 3))];
      }
      #pragma unroll
      for (int tn = 0; tn < 4; ++tn) {
        int n = fc * 128 + wc * 64 + tn * 16 + l15;
        bfr[tn] = *(const bf16x8*)&W1T[n * HD + ks * 32 + lg * 8];
      }
      #pragma unroll
      for (int tm = 0; tm < 2; ++tm)
        #pragma unroll
        for (int tn = 0; tn < 4; ++tn)
          acc1[tm][tn] = __builtin_amdgcn_mfma_f32_16x16x32_bf16(af[tm], bfr[tn], acc1[tm][tn], 0, 0, 0);
    }
    __syncthreads();
    #pragma unroll
    for (int tm = 0; tm < 2; ++tm)
      #pragma unroll
      for (int tn = 0; tn < 4; ++tn) {
        int col = wc * 64 + tn * 16 + l15;
        float bias = b1L[fc * 128 + col];
        #pragma unroll
        for (int ii = 0; ii < 4; ++ii) {
          int r = wr * 32 + tm * 16 + lg * 4 + ii;
          float hv = fmaxf(acc1[tm][tn][ii] + bias, 0.f);
          hL[r * HD + (col ^ ((r & 7) << 3))] = f2bf(hv);
        }
      }
    __syncthreads();
    #pragma unroll
    for (int ks = 0; ks < 4; ++ks) {
      bf16x8 af[2], bfr[4];
      #pragma unroll
      for (int tm = 0; tm < 2; ++tm) {
        int mrow = wr * 32 + tm * 16 + l15;
        af[tm] = *(const bf16x8*)&hL[mrow * HD + ((ks * 32 + lg * 8) ^ ((mrow & 7) << 3))];
      }
      #pragma unroll
      for (int tn = 0; tn < 4; ++tn) {
        int n = wc * 64 + tn * 16 + l15;
        bfr[tn] = *(const bf16x8*)&W2T[n * FD + fc * 128 + ks * 32 + lg * 8];
      }
      #pragma unroll
      for (int tm = 0; tm < 2; ++tm)
        #pragma unroll
        for (int tn = 0; tn < 4; ++tn)
          acc2[tm][tn] = __builtin_amdgcn_mfma_f32_16x16x32_bf16(af[tm], bfr[tn], acc2[tm][tn], 0, 0, 0);
    }
  }

  float res[2][4][4];
  #pragma unroll
  for (int tm = 0; tm < 2; ++tm)
    #pragma unroll
    for (int tn = 0; tn < 4; ++tn) {
      int col = wc * 64 + tn * 16 + l15;
      #pragma unroll
      for (int ii = 0; ii < 4; ++ii) {
        int r = wr * 32 + tm * 16 + lg * 4 + ii;
        res[tm][tn][ii] = bf2f(aL[r * HD + (col ^ ((r & 7) << 3))]);
      }
    }
  __syncthreads();

  #pragma unroll
  for (int tm = 0; tm < 2; ++tm)
    #pragma unroll
    for (int tn = 0; tn < 4; ++tn) {
      int col = wc * 64 + tn * 16 + l15;
      float bias = b2[col];
      #pragma unroll
      for (int ii = 0; ii < 4; ++ii) {
        int r = wr * 32 + tm * 16 + lg * 4 + ii;
        epi[r * 132 + col] = acc2[tm][tn][ii] + bias + res[tm][tn][ii];
      }
    }
  __syncthreads();
  {
    int r = t >> 2, sgi = t & 3;
    const float* rowp = &epi[r * 132 + sgi * 32];
    float sum = 0.f, sq = 0.f;
    #pragma unroll
    for (int u = 0; u < 32; u += 4) {
      float4 v4 = *(const float4*)&rowp[u];
      sum += v4.x + v4.y + v4.z + v4.w;
      sq  += v4.x * v4.x + v4.y * v4.y + v4.z * v4.z + v4.w * v4.w;
    }
    sum += __shfl_xor(sum, 1); sq += __shfl_xor(sq, 1);
    sum += __shfl_xor(sum, 2); sq += __shfl_xor(sq, 2);
    float m = sum * (1.f / HD);
    float var = sq * (1.f / HD) - m * m;
    float rs = rsqrtf(var + LNEPS);
    #pragma unroll
    for (int u = 0; u < 32; u += 4) {
      float4 v4 = *(const float4*)&rowp[u];
      int cb = sgi * 32 + u;
      float4 o;
      o.x = (v4.x - m) * rs * g[cb + 0] + bb[cb + 0];
      o.y = (v4.y - m) * rs * g[cb + 1] + bb[cb + 1];
      o.z = (v4.z - m) * rs * g[cb + 2] + bb[cb + 2];
      o.w = (v4.w - m) * rs * g[cb + 3] + bb[cb + 3];
      *(float4*)&out2[(row0 + r) * HD + cb] = o;
    }
  }
}

// ---------------- K6: e-FFN, bf16 MFMA, fragment-major ws weights --------------
// R14: R12 + double-buffered hidden tile (hL0/hL1) — ONE barrier per fc instead
// of two. Write-safety: hL[fc&1]'s previous readers (GEMM2 of fc-2) are behind
// the fc-1 barrier. Grid 1024, 4 chunks x 64 rows, LDS 52.2KB.
__global__ __launch_bounds__(256) void ffn_mfma_e(
    const float* in1,
    const unsigned short* __restrict__ W1F, const float* __restrict__ b1,
    const unsigned short* __restrict__ W2F, const float* __restrict__ b2,
    const float* __restrict__ g, const float* __restrict__ bb,
    float* out2) {
  const int t = threadIdx.x;
  const int w = t >> 6, l = t & 63;
  const int wr = w >> 1, wc = w & 1;
  const int l15 = l & 15, lg = l >> 4;
  const int rowbase = blockIdx.x * 256;      // 1024 blocks * 256 rows = 262144

  __shared__ __align__(16) char smem[52224];
  unsigned short* aL  = (unsigned short*)smem;            // [64][128] bf16 swz
  unsigned short* hL0 = (unsigned short*)(smem + 16384);  // [64][128] bf16 swz
  unsigned short* hL1 = (unsigned short*)(smem + 32768);  // [64][128] bf16 swz
  float* b1L  = (float*)(smem + 49152);                   // 512 f32
  float* redS = (float*)(smem + 51200);                   // [64][2]
  float* redQ = (float*)(smem + 51712);                   // [64][2]

  for (int v = t; v < FD; v += 256) b1L[v] = b1[v];

  for (int ch = 0; ch < 4; ++ch) {
    const int row0 = rowbase + ch * 64;
    __syncthreads();   // prev-chunk LDS readers done before restage; b1L vis at ch=0

    for (int v = t; v < 64 * 16; v += 256) {
      int r = v >> 4, c8 = (v & 15) << 3;
      const float* src = &in1[(row0 + r) * HD + c8];
      float4 f0 = *(const float4*)src;
      float4 f1 = *(const float4*)(src + 4);
      union { bf16x8 v8; unsigned short u[8]; } pk;
      pk.u[0] = f2bf(f0.x); pk.u[1] = f2bf(f0.y); pk.u[2] = f2bf(f0.z); pk.u[3] = f2bf(f0.w);
      pk.u[4] = f2bf(f1.x); pk.u[5] = f2bf(f1.y); pk.u[6] = f2bf(f1.z); pk.u[7] = f2bf(f1.w);
      *(bf16x8*)&aL[r * HD + (c8 ^ ((r & 7) << 3))] = pk.v8;
    }
    __syncthreads();

    f32x4 acc2[2][4];
    #pragma unroll
    for (int tm = 0; tm < 2; ++tm)
      #pragma unroll
      for (int tn = 0; tn < 4; ++tn) acc2[tm][tn] = (f32x4){0.f, 0.f, 0.f, 0.f};

    #pragma unroll
    for (int fc = 0; fc < 4; ++fc) {
      unsigned short* hLp = (fc & 1) ? hL1 : hL0;
      f32x4 acc1[2][4];
      #pragma unroll
      for (int tm = 0; tm < 2; ++tm)
        #pragma unroll
        for (int tn = 0; tn < 4; ++tn) acc1[tm][tn] = (f32x4){0.f, 0.f, 0.f, 0.f};
      #pragma unroll
      for (int ks = 0; ks < 4; ++ks) {
        bf16x8 af[2], bfr[4];
        #pragma unroll
        for (int tm = 0; tm < 2; ++tm) {
          int mrow = wr * 32 + tm * 16 + l15;
          af[tm] = *(const bf16x8*)&aL[mrow * HD + ((ks * 32 + lg * 8) ^ ((mrow & 7) << 3))];
        }
        #pragma unroll
        for (int tn = 0; tn < 4; ++tn) {
          int nt = fc * 8 + wc * 4 + tn;                 // 16-wide n-tile index
          bfr[tn] = *(const bf16x8*)&W1F[(((nt * 4 + ks) * 64) + l) * 8];
        }
        #pragma unroll
        for (int tm = 0; tm < 2; ++tm)
          #pragma unroll
          for (int tn = 0; tn < 4; ++tn)
            acc1[tm][tn] = __builtin_amdgcn_mfma_f32_16x16x32_bf16(af[tm], bfr[tn], acc1[tm][tn], 0, 0, 0);
      }
      // store relu(hidden) into parity buffer — prior readers of hLp are behind
      // the fc-1 barrier (GEMM2 of fc-2); no barrier needed before the store.
      #pragma unroll
      for (int tm = 0; tm < 2; ++tm)
        #pragma unroll
        for (int tn = 0; tn < 4; ++tn) {
          int col = wc * 64 + tn * 16 + l15;
          float bias = b1L[fc * 128 + col];
          #pragma unroll
          for (int ii = 0; ii < 4; ++ii) {
            int r = wr * 32 + tm * 16 + lg * 4 + ii;
            float hv = fmaxf(acc1[tm][tn][ii] + bias, 0.f);
            hLp[r * HD + (col ^ ((r & 7) << 3))] = f2bf(hv);
          }
        }
      __syncthreads();   // hLp visible to all waves
      #pragma unroll
      for (int ks = 0; ks < 4; ++ks) {
        bf16x8 af[2], bfr[4];
        #pragma unroll
        for (int tm = 0; tm < 2; ++tm) {
          int mrow = wr * 32 + tm * 16 + l15;
          af[tm] = *(const bf16x8*)&hLp[mrow * HD + ((ks * 32 + lg * 8) ^ ((mrow & 7) << 3))];
        }
        #pragma unroll
        for (int tn = 0; tn < 4; ++tn) {
          int nt = wc * 4 + tn;                          // n < 128 -> 8 tiles
          int ksg = fc * 4 + ks;                         // k < 512 -> 16 k-steps
          bfr[tn] = *(const bf16x8*)&W2F[(((nt * 16 + ksg) * 64) + l) * 8];
        }
        #pragma unroll
        for (int tm = 0; tm < 2; ++tm)
          #pragma unroll
          for (int tn = 0; tn < 4; ++tn)
            acc2[tm][tn] = __builtin_amdgcn_mfma_f32_16x16x32_bf16(af[tm], bfr[tn], acc2[tm][tn], 0, 0, 0);
      }
    }

    // ---- epilogue: bias + residual (from aL) in regs; row sums via shfl ----
    #pragma unroll
    for (int tm = 0; tm < 2; ++tm) {
      #pragma unroll
      for (int tn = 0; tn < 4; ++tn) {
        int col = wc * 64 + tn * 16 + l15;
        float bias = b2[col];
        #pragma unroll
        for (int ii = 0; ii < 4; ++ii) {
          int r = wr * 32 + tm * 16 + lg * 4 + ii;
          acc2[tm][tn][ii] += bias + bf2f(aL[r * HD + (col ^ ((r & 7) << 3))]);
        }
      }
      #pragma unroll
      for (int ii = 0; ii < 4; ++ii) {
        float s  = acc2[tm][0][ii] + acc2[tm][1][ii] + acc2[tm][2][ii] + acc2[tm][3][ii];
        float sq = acc2[tm][0][ii] * acc2[tm][0][ii] + acc2[tm][1][ii] * acc2[tm][1][ii]
                 + acc2[tm][2][ii] * acc2[tm][2][ii] + acc2[tm][3][ii] * acc2[tm][3][ii];
        #pragma unroll
        for (int off = 1; off < 16; off <<= 1) {
          s += __shfl_xor(s, off); sq += __shfl_xor(sq, off);
        }
        if (l15 == 0) {
          int r = wr * 32 + tm * 16 + lg * 4 + ii;
          redS[r * 2 + wc] = s; redQ[r * 2 + wc] = sq;
        }
      }
    }
    __syncthreads();

    // ---- LN + write (direct from registers) ----
    #pragma unroll
    for (int tm = 0; tm < 2; ++tm) {
      float mrow[4], rsrow[4];
      #pragma unroll
      for (int ii = 0; ii < 4; ++ii) {
        int r = wr * 32 + tm * 16 + lg * 4 + ii;
        float s = redS[r * 2] + redS[r * 2 + 1];
        float sq = redQ[r * 2] + redQ[r * 2 + 1];
        float m = s * (1.f / HD);
        float var = sq * (1.f / HD) - m * m;
        mrow[ii] = m; rsrow[ii] = rsqrtf(var + LNEPS);
      }
      #pragma unroll
      for (int tn = 0; tn < 4; ++tn) {
        int col = wc * 64 + tn * 16 + l15;
        float gv = g[col], bv = bb[col];
        #pragma unroll
        for (int ii = 0; ii < 4; ++ii) {
          int r = wr * 32 + tm * 16 + lg * 4 + ii;
          out2[(row0 + r) * HD + col] = (acc2[tm][tn][ii] - mrow[ii]) * rsrow[ii] * gv + bv;
        }
      }
    }
  }
}

// ---------------- launch -------------------------------------------------------
extern "C" void kernel_launch(void* const* d_in, const int* in_sizes, int n_in,
                              void* d_out, int out_size, void* d_ws, size_t ws_size,
                              hipStream_t stream) {
  const float* x    = (const float*)d_in[0];
  const float* e    = (const float*)d_in[1];
  const float* mask = (const float*)d_in[2];
  const float* Wq   = (const float*)d_in[3];
  const float* bq   = (const float*)d_in[4];
  const float* Wk   = (const float*)d_in[5];
  const float* bk   = (const float*)d_in[6];
  const float* We   = (const float*)d_in[9];
  const float* be   = (const float*)d_in[10];
  const float* Woh  = (const float*)d_in[11];
  const float* boh  = (const float*)d_in[12];
  const float* Woe  = (const float*)d_in[13];
  const float* boe  = (const float*)d_in[14];
  const float* Wf1x = (const float*)d_in[15];
  const float* bf1x = (const float*)d_in[16];
  const float* Wf2x = (const float*)d_in[17];
  const float* bf2x = (const float*)d_in[18];
  const float* Wf1e = (const float*)d_in[19];
  const float* bf1e = (const float*)d_in[20];
  const float* Wf2e = (const float*)d_in[21];
  const float* bf2e = (const float*)d_in[22];
  const float* g1x  = (const float*)d_in[23];
  const float* b1x  = (const float*)d_in[24];
  const float* g1e  = (const float*)d_in[25];
  const float* b1e  = (const float*)d_in[26];

  float* xout = (float*)d_out;                 // x2: 4*256*128
  float* eout = (float*)d_out + 131072;        // e2 (holds e1 mid-pipeline)

  char* ws = (char*)d_ws;
  unsigned short* W1Fe = (unsigned short*)(ws);            // 128 KB (fragment-major)
  unsigned short* W2Fe = (unsigned short*)(ws + 131072);   // 128 KB (fragment-major)
  unsigned short* W1Tx = (unsigned short*)(ws + 262144);   // 128 KB ([n][k])
  unsigned short* W2Tx = (unsigned short*)(ws + 393216);   // 128 KB ([n][k])
  float* Qs  = (float*)(ws + 524288);                      // 512 KB
  float* Kp  = (float*)(ws + 1048576);                     // 512 KB
  float* x1b = (float*)(ws + 1572864);                     // 512 KB
  float* S   = (float*)(ws + 2097152);                     // 8 MB (in-place softmax)

  prep_weights<<<64, 256, 0, stream>>>(Wf1x, Wf2x, Wf1e, Wf2e, W1Tx, W2Tx, W1Fe, W2Fe);
  qk_proj<<<1024, 128, 0, stream>>>(x, Wq, bq, Wk, bk, Qs, Kp);
  edge_attn<<<4096, 256, 0, stream>>>(e, We, be, Woe, boe, Qs, Kp, g1e, b1e, S, eout);
  softmax_k<<<8192, 256, 0, stream>>>(S, mask);
  x_attn_ln<<<1024, 128, 0, stream>>>(x, S, Kp, Woh, boh, g1x, b1x, x1b);
  ffn_mfma<<<16, 256, 0, stream>>>(x1b, W1Tx, bf1x, W2Tx, bf2x, g1x, b1x, xout);
  ffn_mfma_e<<<1024, 256, 0, stream>>>(eout, W1Fe, bf1e, W2Fe, bf2e, g1e, b1e, eout);
}

// Round 15
// 390.805 us; speedup vs baseline: 1.4980x; 1.4980x over previous
//
#include <hip/hip_runtime.h>
#include <math.h>

#define NSEQ 256
#define HD 128
#define FD 512
#define NHD 8
#define LNEPS 1e-5f

typedef __attribute__((ext_vector_type(8))) short bf16x8;
typedef __attribute__((ext_vector_type(4))) float f32x4;

__device__ __forceinline__ unsigned short f2bf(float x) {
  union { float f; unsigned int u; } v; v.f = x;
  unsigned int r = v.u + 0x7fffu + ((v.u >> 16) & 1u);
  return (unsigned short)(r >> 16);
}

__device__ __forceinline__ float bf2f(unsigned short u) {
  union { float f; unsigned int v; } cv; cv.v = ((unsigned int)u) << 16;
  return cv.f;
}

// ---------------- K0: prep weights ---------------------------------------------
// x-path: [n][k]. e-path: FRAGMENT-MAJOR (each 16x32 B-tile = 64 consecutive
// 16B lane-chunks; lane l reads chunk l — fully coalesced). R11/R12-proven.
__global__ void prep_weights(
    const float* __restrict__ W1x, const float* __restrict__ W2x,
    const float* __restrict__ W1e, const float* __restrict__ W2e,
    unsigned short* __restrict__ W1Tx, unsigned short* __restrict__ W2Tx,
    unsigned short* __restrict__ W1Fe, unsigned short* __restrict__ W2Fe) {
  int t = blockIdx.x * 256 + threadIdx.x;
  int tot = gridDim.x * 256;
  for (int idx = t; idx < FD * HD; idx += tot) {       // W1: k<128, n<512
    int n = idx >> 7, k = idx & (HD - 1);
    W1Tx[idx] = f2bf(W1x[k * FD + n]);
    float ve = W1e[k * FD + n];
    int dst = ((((n >> 4) * 4 + (k >> 5)) * 64) + ((k >> 3) & 3) * 16 + (n & 15)) * 8 + (k & 7);
    W1Fe[dst] = f2bf(ve);
  }
  for (int idx = t; idx < HD * FD; idx += tot) {       // W2: k<512, n<128
    int n = idx >> 9, k = idx & (FD - 1);
    W2Tx[idx] = f2bf(W2x[k * HD + n]);
    float ve = W2e[k * HD + n];
    int dst = ((((n >> 4) * 16 + (k >> 5)) * 64) + ((k >> 3) & 3) * 16 + (n & 15)) * 8 + (k & 7);
    W2Fe[dst] = f2bf(ve);
  }
}

// ---------------- K1: Q,K projections (V reuses K per the reference bug) --------
__global__ __launch_bounds__(128) void qk_proj(const float* __restrict__ x,
    const float* __restrict__ Wq, const float* __restrict__ bq,
    const float* __restrict__ Wk, const float* __restrict__ bk,
    float* __restrict__ Qs, float* __restrict__ Kp) {
  int row = blockIdx.x;         // b*N+i
  int c = threadIdx.x;
  __shared__ float xl[HD];
  xl[c] = x[row * HD + c];
  __syncthreads();
  float aq = bq[c], ak = bk[c];
  #pragma unroll 8
  for (int k = 0; k < HD; ++k) {
    float xv = xl[k];
    aq = fmaf(xv, Wq[k * HD + c], aq);
    ak = fmaf(xv, Wk[k * HD + c], ak);
  }
  Qs[row * HD + c] = aq * 0.25f;   // fold scale = 1/sqrt(16)
  Kp[row * HD + c] = ak;
}

// ---------------- K2: fused edge attention, bf16 MFMA (R8-proven) --------------
__global__ __launch_bounds__(256) void edge_attn(
    const float* __restrict__ e,
    const float* __restrict__ We, const float* __restrict__ be,
    const float* __restrict__ Woe, const float* __restrict__ boe,
    const float* __restrict__ Qs, const float* __restrict__ Kp,
    const float* __restrict__ g1e, const float* __restrict__ b1e,
    float* __restrict__ Sout, float* __restrict__ e1out) {
  const int gid = blockIdx.x;
  const int jt = gid & 3, i = (gid >> 2) & (NSEQ - 1), b = gid >> 10;
  const int j0 = jt * 64;
  const int t = threadIdx.x;
  const int w = t >> 6, l = t & 63;
  const int wr = w >> 1, wc = w & 1;
  const int l15 = l & 15, lg = l >> 4;

  __shared__ unsigned short eL[64 * 128];   // e tile bf16 swizzled; later holds P
  __shared__ unsigned short kL[64 * 136];   // K tile bf16, padded (no swizzle)
  __shared__ float qL[HD], beL[HD], boeL[HD], gL[HD], bbL[HD];
  __shared__ float redS[64][2], redQ[64][2];

  if (t < HD) {
    qL[t]   = Qs[(b * NSEQ + i) * HD + t];
    beL[t]  = be[t];
    boeL[t] = boe[t];
    gL[t]   = g1e[t];
    bbL[t]  = b1e[t];
  }
  const int ebase = ((b * NSEQ + i) * NSEQ + j0) * HD;
  for (int v = t; v < 64 * 16; v += 256) {
    int r = v >> 4, c8 = (v & 15) << 3;
    const float* se = &e[ebase + r * HD + c8];
    float4 e0 = *(const float4*)se;
    float4 e1v = *(const float4*)(se + 4);
    union { bf16x8 v8; unsigned short u[8]; } pk;
    pk.u[0] = f2bf(e0.x); pk.u[1] = f2bf(e0.y); pk.u[2] = f2bf(e0.z); pk.u[3] = f2bf(e0.w);
    pk.u[4] = f2bf(e1v.x); pk.u[5] = f2bf(e1v.y); pk.u[6] = f2bf(e1v.z); pk.u[7] = f2bf(e1v.w);
    *(bf16x8*)&eL[r * HD + (c8 ^ ((r & 7) << 3))] = pk.v8;
    const float* sk = &Kp[(b * NSEQ + j0 + r) * HD + c8];
    float4 k0 = *(const float4*)sk;
    float4 k1 = *(const float4*)(sk + 4);
    pk.u[0] = f2bf(k0.x); pk.u[1] = f2bf(k0.y); pk.u[2] = f2bf(k0.z); pk.u[3] = f2bf(k0.w);
    pk.u[4] = f2bf(k1.x); pk.u[5] = f2bf(k1.y); pk.u[6] = f2bf(k1.z); pk.u[7] = f2bf(k1.w);
    *(bf16x8*)&kL[r * 136 + c8] = pk.v8;
  }
  __syncthreads();

  // ---- GEMM1: Ee = e @ We + be ----
  f32x4 acc1[2][4];
  #pragma unroll
  for (int tm = 0; tm < 2; ++tm)
    #pragma unroll
    for (int tn = 0; tn < 4; ++tn) {
      float bv = beL[wc * 64 + tn * 16 + l15];
      acc1[tm][tn] = (f32x4){bv, bv, bv, bv};
    }
  #pragma unroll
  for (int ks = 0; ks < 4; ++ks) {
    bf16x8 af[2], bfr[4];
    #pragma unroll
    for (int tm = 0; tm < 2; ++tm) {
      int mrow = wr * 32 + tm * 16 + l15;
      af[tm] = *(const bf16x8*)&eL[mrow * HD + ((ks * 32 + lg * 8) ^ ((mrow & 7) << 3))];
    }
    #pragma unroll
    for (int tn = 0; tn < 4; ++tn) {
      int n = wc * 64 + tn * 16 + l15;
      const float* wp = &We[(ks * 32 + lg * 8) * HD + n];
      union { bf16x8 v8; unsigned short u[8]; } pk;
      #pragma unroll
      for (int ii = 0; ii < 8; ++ii) pk.u[ii] = f2bf(wp[ii * HD]);
      bfr[tn] = pk.v8;
    }
    #pragma unroll
    for (int tm = 0; tm < 2; ++tm)
      #pragma unroll
      for (int tn = 0; tn < 4; ++tn)
        acc1[tm][tn] = __builtin_amdgcn_mfma_f32_16x16x32_bf16(af[tm], bfr[tn], acc1[tm][tn], 0, 0, 0);
  }

  // ---- P = Ee * q * k; head-sums -> S ----
  #pragma unroll
  for (int tm = 0; tm < 2; ++tm)
    #pragma unroll
    for (int tn = 0; tn < 4; ++tn) {
      int c = wc * 64 + tn * 16 + l15;
      float qv = qL[c];
      f32x4 p;
      #pragma unroll
      for (int ii = 0; ii < 4; ++ii) {
        int r = wr * 32 + tm * 16 + lg * 4 + ii;
        p[ii] = acc1[tm][tn][ii] * qv * bf2f(kL[r * 136 + c]);
      }
      acc1[tm][tn] = p;
      float h0 = p[0], h1 = p[1], h2 = p[2], h3 = p[3];
      #pragma unroll
      for (int off = 1; off < 16; off <<= 1) {
        h0 += __shfl_xor(h0, off); h1 += __shfl_xor(h1, off);
        h2 += __shfl_xor(h2, off); h3 += __shfl_xor(h3, off);
      }
      if (l15 < 4) {
        float val = l15 == 0 ? h0 : l15 == 1 ? h1 : l15 == 2 ? h2 : h3;
        int r = wr * 32 + tm * 16 + lg * 4 + l15;
        Sout[((b * NHD + (wc * 4 + tn)) * NSEQ + i) * NSEQ + j0 + r] = val;
      }
    }
  __syncthreads();

  // ---- store P (bf16) into eL region ----
  #pragma unroll
  for (int tm = 0; tm < 2; ++tm)
    #pragma unroll
    for (int tn = 0; tn < 4; ++tn) {
      int c = wc * 64 + tn * 16 + l15;
      #pragma unroll
      for (int ii = 0; ii < 4; ++ii) {
        int r = wr * 32 + tm * 16 + lg * 4 + ii;
        eL[r * HD + (c ^ ((r & 7) << 3))] = f2bf(acc1[tm][tn][ii]);
      }
    }
  __syncthreads();

  // ---- GEMM2: e_attn = P @ Woe + boe ----
  f32x4 acc2[2][4];
  #pragma unroll
  for (int tm = 0; tm < 2; ++tm)
    #pragma unroll
    for (int tn = 0; tn < 4; ++tn) {
      float bv = boeL[wc * 64 + tn * 16 + l15];
      acc2[tm][tn] = (f32x4){bv, bv, bv, bv};
    }
  #pragma unroll
  for (int ks = 0; ks < 4; ++ks) {
    bf16x8 af[2], bfr[4];
    #pragma unroll
    for (int tm = 0; tm < 2; ++tm) {
      int mrow = wr * 32 + tm * 16 + l15;
      af[tm] = *(const bf16x8*)&eL[mrow * HD + ((ks * 32 + lg * 8) ^ ((mrow & 7) << 3))];
    }
    #pragma unroll
    for (int tn = 0; tn < 4; ++tn) {
      int n = wc * 64 + tn * 16 + l15;
      const float* wp = &Woe[(ks * 32 + lg * 8) * HD + n];
      union { bf16x8 v8; unsigned short u[8]; } pk;
      #pragma unroll
      for (int ii = 0; ii < 8; ++ii) pk.u[ii] = f2bf(wp[ii * HD]);
      bfr[tn] = pk.v8;
    }
    #pragma unroll
    for (int tm = 0; tm < 2; ++tm)
      #pragma unroll
      for (int tn = 0; tn < 4; ++tn)
        acc2[tm][tn] = __builtin_amdgcn_mfma_f32_16x16x32_bf16(af[tm], bfr[tn], acc2[tm][tn], 0, 0, 0);
  }

  // ---- + e residual; LN partials via shfl ----
  #pragma unroll
  for (int tm = 0; tm < 2; ++tm) {
    #pragma unroll
    for (int tn = 0; tn < 4; ++tn) {
      int c = wc * 64 + tn * 16 + l15;
      #pragma unroll
      for (int ii = 0; ii < 4; ++ii) {
        int r = wr * 32 + tm * 16 + lg * 4 + ii;
        acc2[tm][tn][ii] += e[ebase + r * HD + c];
      }
    }
    #pragma unroll
    for (int ii = 0; ii < 4; ++ii) {
      float s  = acc2[tm][0][ii] + acc2[tm][1][ii] + acc2[tm][2][ii] + acc2[tm][3][ii];
      float sq = acc2[tm][0][ii] * acc2[tm][0][ii] + acc2[tm][1][ii] * acc2[tm][1][ii]
               + acc2[tm][2][ii] * acc2[tm][2][ii] + acc2[tm][3][ii] * acc2[tm][3][ii];
      #pragma unroll
      for (int off = 1; off < 16; off <<= 1) {
        s += __shfl_xor(s, off); sq += __shfl_xor(sq, off);
      }
      if (l15 == 0) {
        int r = wr * 32 + tm * 16 + lg * 4 + ii;
        redS[r][wc] = s; redQ[r][wc] = sq;
      }
    }
  }
  __syncthreads();

  // ---- LN + write e1 ----
  #pragma unroll
  for (int tm = 0; tm < 2; ++tm) {
    float mrow[4], rsrow[4];
    #pragma unroll
    for (int ii = 0; ii < 4; ++ii) {
      int r = wr * 32 + tm * 16 + lg * 4 + ii;
      float s = redS[r][0] + redS[r][1];
      float sq = redQ[r][0] + redQ[r][1];
      float m = s * (1.f / HD);
      float var = sq * (1.f / HD) - m * m;
      mrow[ii] = m; rsrow[ii] = rsqrtf(var + LNEPS);
    }
    #pragma unroll
    for (int tn = 0; tn < 4; ++tn) {
      int c = wc * 64 + tn * 16 + l15;
      float gv = gL[c], bv = bbL[c];
      #pragma unroll
      for (int ii = 0; ii < 4; ++ii) {
        int r = wr * 32 + tm * 16 + lg * 4 + ii;
        e1out[ebase + r * HD + c] = (acc2[tm][tn][ii] - mrow[ii]) * rsrow[ii] * gv + bv;
      }
    }
  }
}

// ---------------- K3: softmax over j, IN PLACE on S ----------------------------
__global__ __launch_bounds__(256) void softmax_k(float* __restrict__ S,
    const float* __restrict__ mask) {
  int row = blockIdx.x;               // (b*8+h)*256+i
  int t = threadIdx.x;
  int idx = row * NSEQ + t;
  float v = S[idx] + mask[idx];
  float m = v;
  #pragma unroll
  for (int off = 1; off < 64; off <<= 1) m = fmaxf(m, __shfl_xor(m, off));
  __shared__ float wbuf[8];
  if ((t & 63) == 0) wbuf[t >> 6] = m;
  __syncthreads();
  m = fmaxf(fmaxf(wbuf[0], wbuf[1]), fmaxf(wbuf[2], wbuf[3]));
  float ex = __expf(v - m);
  float s = ex;
  #pragma unroll
  for (int off = 1; off < 64; off <<= 1) s += __shfl_xor(s, off);
  __syncthreads();
  if ((t & 63) == 0) wbuf[4 + (t >> 6)] = s;
  __syncthreads();
  s = wbuf[4] + wbuf[5] + wbuf[6] + wbuf[7];
  S[idx] = ex / s;   // safe: all reads of S complete before first barrier
}

// ---------------- K4: x attention + LN1 -> x1 ----------------------------------
__global__ __launch_bounds__(128) void x_attn_ln(
    const float* __restrict__ x, const float* __restrict__ scores,
    const float* __restrict__ Kp,
    const float* __restrict__ Woh, const float* __restrict__ boh,
    const float* __restrict__ g1x, const float* __restrict__ b1x,
    float* __restrict__ x1out) {
  int bi = blockIdx.x; int b = bi >> 8; int i = bi & 255;
  int c = threadIdx.x;
  __shared__ float sL[NHD * NSEQ];
  __shared__ float attL[HD];
  __shared__ float rbuf[4];

  for (int v = c; v < NHD * NSEQ; v += 128) {
    int h = v >> 8, j = v & 255;
    sL[v] = scores[((b * NHD + h) * NSEQ + i) * NSEQ + j];
  }
  __syncthreads();
  int h = c >> 4;
  float att = 0.f;
  for (int j = 0; j < NSEQ; ++j)
    att = fmaf(sL[h * NSEQ + j], Kp[(b * NSEQ + j) * HD + c], att);   // V = K
  attL[c] = att;
  __syncthreads();
  float o = boh[c];
  for (int k = 0; k < HD; ++k) o = fmaf(attL[k], Woh[k * HD + c], o);
  o += x[bi * HD + c];
  float s = o, s2 = o * o;
  #pragma unroll
  for (int off = 1; off < 64; off <<= 1) { s += __shfl_xor(s, off); s2 += __shfl_xor(s2, off); }
  if ((c & 63) == 0) { rbuf[(c >> 6) * 2] = s; rbuf[(c >> 6) * 2 + 1] = s2; }
  __syncthreads();
  s = rbuf[0] + rbuf[2]; s2 = rbuf[1] + rbuf[3];
  float m = s * (1.f / HD);
  float var = s2 * (1.f / HD) - m * m;
  x1out[bi * HD + c] = (o - m) * rsqrtf(var + LNEPS) * g1x[c] + b1x[c];
}

// ---------------- K5: x-FFN, bf16 MFMA, [n][k] ws weights (R4-proven) ----------
__global__ __launch_bounds__(256) void ffn_mfma(
    const float* in1,
    const unsigned short* __restrict__ W1T, const float* __restrict__ b1,
    const unsigned short* __restrict__ W2T, const float* __restrict__ b2,
    const float* __restrict__ g, const float* __restrict__ bb,
    float* out2) {
  const int row0 = blockIdx.x * 64;
  const int t = threadIdx.x;
  const int w = t >> 6, l = t & 63;
  const int wr = w >> 1, wc = w & 1;
  const int l15 = l & 15, lg = l >> 4;

  __shared__ __align__(16) char smem[34816];
  unsigned short* aL = (unsigned short*)smem;
  unsigned short* hL = (unsigned short*)(smem + 16384);
  float* b1L = (float*)(smem + 32768);
  float* epi = (float*)smem;

  for (int v = t; v < 64 * 16; v += 256) {
    int r = v >> 4, c8 = (v & 15) << 3;
    const float* src = &in1[(row0 + r) * HD + c8];
    float4 f0 = *(const float4*)src;
    float4 f1 = *(const float4*)(src + 4);
    union { bf16x8 v8; unsigned short u[8]; } pk;
    pk.u[0] = f2bf(f0.x); pk.u[1] = f2bf(f0.y); pk.u[2] = f2bf(f0.z); pk.u[3] = f2bf(f0.w);
    pk.u[4] = f2bf(f1.x); pk.u[5] = f2bf(f1.y); pk.u[6] = f2bf(f1.z); pk.u[7] = f2bf(f1.w);
    *(bf16x8*)&aL[r * HD + (c8 ^ ((r & 7) << 3))] = pk.v8;
  }
  for (int v = t; v < FD; v += 256) b1L[v] = b1[v];
  __syncthreads();

  f32x4 acc2[2][4];
  #pragma unroll
  for (int tm = 0; tm < 2; ++tm)
    #pragma unroll
    for (int tn = 0; tn < 4; ++tn) acc2[tm][tn] = (f32x4){0.f, 0.f, 0.f, 0.f};

  for (int fc = 0; fc < 4; ++fc) {
    f32x4 acc1[2][4];
    #pragma unroll
    for (int tm = 0; tm < 2; ++tm)
      #pragma unroll
      for (int tn = 0; tn < 4; ++tn) acc1[tm][tn] = (f32x4){0.f, 0.f, 0.f, 0.f};
    #pragma unroll
    for (int ks = 0; ks < 4; ++ks) {
      bf16x8 af[2], bfr[4];
      #pragma unroll
      for (int tm = 0; tm < 2; ++tm) {
        int mrow = wr * 32 + tm * 16 + l15;
        af[tm] = *(const bf16x8*)&aL[mrow * HD + ((ks * 32 + lg * 8) ^ ((mrow & 7) << 3))];
      }
      #pragma unroll
      for (int tn = 0; tn < 4; ++tn) {
        int n = fc * 128 + wc * 64 + tn * 16 + l15;
        bfr[tn] = *(const bf16x8*)&W1T[n * HD + ks * 32 + lg * 8];
      }
      #pragma unroll
      for (int tm = 0; tm < 2; ++tm)
        #pragma unroll
        for (int tn = 0; tn < 4; ++tn)
          acc1[tm][tn] = __builtin_amdgcn_mfma_f32_16x16x32_bf16(af[tm], bfr[tn], acc1[tm][tn], 0, 0, 0);
    }
    __syncthreads();
    #pragma unroll
    for (int tm = 0; tm < 2; ++tm)
      #pragma unroll
      for (int tn = 0; tn < 4; ++tn) {
        int col = wc * 64 + tn * 16 + l15;
        float bias = b1L[fc * 128 + col];
        #pragma unroll
        for (int ii = 0; ii < 4; ++ii) {
          int r = wr * 32 + tm * 16 + lg * 4 + ii;
          float hv = fmaxf(acc1[tm][tn][ii] + bias, 0.f);
          hL[r * HD + (col ^ ((r & 7) << 3))] = f2bf(hv);
        }
      }
    __syncthreads();
    #pragma unroll
    for (int ks = 0; ks < 4; ++ks) {
      bf16x8 af[2], bfr[4];
      #pragma unroll
      for (int tm = 0; tm < 2; ++tm) {
        int mrow = wr * 32 + tm * 16 + l15;
        af[tm] = *(const bf16x8*)&hL[mrow * HD + ((ks * 32 + lg * 8) ^ ((mrow & 7) << 3))];
      }
      #pragma unroll
      for (int tn = 0; tn < 4; ++tn) {
        int n = wc * 64 + tn * 16 + l15;
        bfr[tn] = *(const bf16x8*)&W2T[n * FD + fc * 128 + ks * 32 + lg * 8];
      }
      #pragma unroll
      for (int tm = 0; tm < 2; ++tm)
        #pragma unroll
        for (int tn = 0; tn < 4; ++tn)
          acc2[tm][tn] = __builtin_amdgcn_mfma_f32_16x16x32_bf16(af[tm], bfr[tn], acc2[tm][tn], 0, 0, 0);
    }
  }

  float res[2][4][4];
  #pragma unroll
  for (int tm = 0; tm < 2; ++tm)
    #pragma unroll
    for (int tn = 0; tn < 4; ++tn) {
      int col = wc * 64 + tn * 16 + l15;
      #pragma unroll
      for (int ii = 0; ii < 4; ++ii) {
        int r = wr * 32 + tm * 16 + lg * 4 + ii;
        res[tm][tn][ii] = bf2f(aL[r * HD + (col ^ ((r & 7) << 3))]);
      }
    }
  __syncthreads();

  #pragma unroll
  for (int tm = 0; tm < 2; ++tm)
    #pragma unroll
    for (int tn = 0; tn < 4; ++tn) {
      int col = wc * 64 + tn * 16 + l15;
      float bias = b2[col];
      #pragma unroll
      for (int ii = 0; ii < 4; ++ii) {
        int r = wr * 32 + tm * 16 + lg * 4 + ii;
        epi[r * 132 + col] = acc2[tm][tn][ii] + bias + res[tm][tn][ii];
      }
    }
  __syncthreads();
  {
    int r = t >> 2, sgi = t & 3;
    const float* rowp = &epi[r * 132 + sgi * 32];
    float sum = 0.f, sq = 0.f;
    #pragma unroll
    for (int u = 0; u < 32; u += 4) {
      float4 v4 = *(const float4*)&rowp[u];
      sum += v4.x + v4.y + v4.z + v4.w;
      sq  += v4.x * v4.x + v4.y * v4.y + v4.z * v4.z + v4.w * v4.w;
    }
    sum += __shfl_xor(sum, 1); sq += __shfl_xor(sq, 1);
    sum += __shfl_xor(sum, 2); sq += __shfl_xor(sq, 2);
    float m = sum * (1.f / HD);
    float var = sq * (1.f / HD) - m * m;
    float rs = rsqrtf(var + LNEPS);
    #pragma unroll
    for (int u = 0; u < 32; u += 4) {
      float4 v4 = *(const float4*)&rowp[u];
      int cb = sgi * 32 + u;
      float4 o;
      o.x = (v4.x - m) * rs * g[cb + 0] + bb[cb + 0];
      o.y = (v4.y - m) * rs * g[cb + 1] + bb[cb + 1];
      o.z = (v4.z - m) * rs * g[cb + 2] + bb[cb + 2];
      o.w = (v4.w - m) * rs * g[cb + 3] + bb[cb + 3];
      *(float4*)&out2[(row0 + r) * HD + cb] = o;
    }
  }
}

// ---------------- K6: e-FFN, bf16 MFMA, fragment-major ws weights --------------
// R15: R12 structure with 512 threads / 8 waves per block — each wave owns a
// 16x64 sub-tile (wr 0..3, wc 0..1; tm dimension removed). Lower VGPR, same
// LDS (35.8KB), 2x wave pool for latency hiding. Grid 1024, 4 chunks x 64 rows.
__global__ __launch_bounds__(512) void ffn_mfma_e(
    const float* in1,
    const unsigned short* __restrict__ W1F, const float* __restrict__ b1,
    const unsigned short* __restrict__ W2F, const float* __restrict__ b2,
    const float* __restrict__ g, const float* __restrict__ bb,
    float* out2) {
  const int t = threadIdx.x;
  const int w = t >> 6, l = t & 63;
  const int wr = w >> 1, wc = w & 1;          // wr 0..3 (16-row strip), wc 0..1
  const int l15 = l & 15, lg = l >> 4;
  const int rowbase = blockIdx.x * 256;       // 1024 blocks * 256 rows = 262144

  __shared__ __align__(16) char smem[35840];
  unsigned short* aL = (unsigned short*)smem;             // [64][128] bf16 swizzled
  unsigned short* hL = (unsigned short*)(smem + 16384);   // [64][128] bf16 swizzled
  float* b1L  = (float*)(smem + 32768);                   // 512 f32
  float* redS = (float*)(smem + 34816);                   // [64][2]
  float* redQ = (float*)(smem + 35328);                   // [64][2]

  for (int v = t; v < FD; v += 512) b1L[v] = b1[v];

  for (int ch = 0; ch < 4; ++ch) {
    const int row0 = rowbase + ch * 64;
    __syncthreads();   // prev-chunk LDS readers done before restage; b1L vis at ch=0

    for (int v = t; v < 64 * 16; v += 512) {
      int r = v >> 4, c8 = (v & 15) << 3;
      const float* src = &in1[(row0 + r) * HD + c8];
      float4 f0 = *(const float4*)src;
      float4 f1 = *(const float4*)(src + 4);
      union { bf16x8 v8; unsigned short u[8]; } pk;
      pk.u[0] = f2bf(f0.x); pk.u[1] = f2bf(f0.y); pk.u[2] = f2bf(f0.z); pk.u[3] = f2bf(f0.w);
      pk.u[4] = f2bf(f1.x); pk.u[5] = f2bf(f1.y); pk.u[6] = f2bf(f1.z); pk.u[7] = f2bf(f1.w);
      *(bf16x8*)&aL[r * HD + (c8 ^ ((r & 7) << 3))] = pk.v8;
    }
    __syncthreads();

    f32x4 acc2[4];
    #pragma unroll
    for (int tn = 0; tn < 4; ++tn) acc2[tn] = (f32x4){0.f, 0.f, 0.f, 0.f};

    for (int fc = 0; fc < 4; ++fc) {
      f32x4 acc1[4];
      #pragma unroll
      for (int tn = 0; tn < 4; ++tn) acc1[tn] = (f32x4){0.f, 0.f, 0.f, 0.f};
      #pragma unroll
      for (int ks = 0; ks < 4; ++ks) {
        bf16x8 af, bfr[4];
        int mrow = wr * 16 + l15;
        af = *(const bf16x8*)&aL[mrow * HD + ((ks * 32 + lg * 8) ^ ((mrow & 7) << 3))];
        #pragma unroll
        for (int tn = 0; tn < 4; ++tn) {
          int nt = fc * 8 + wc * 4 + tn;                 // 16-wide n-tile index
          bfr[tn] = *(const bf16x8*)&W1F[(((nt * 4 + ks) * 64) + l) * 8];
        }
        #pragma unroll
        for (int tn = 0; tn < 4; ++tn)
          acc1[tn] = __builtin_amdgcn_mfma_f32_16x16x32_bf16(af, bfr[tn], acc1[tn], 0, 0, 0);
      }
      __syncthreads();   // prev GEMM2 hL reads done (first fc: covered by stage barrier)
      #pragma unroll
      for (int tn = 0; tn < 4; ++tn) {
        int col = wc * 64 + tn * 16 + l15;
        float bias = b1L[fc * 128 + col];
        #pragma unroll
        for (int ii = 0; ii < 4; ++ii) {
          int r = wr * 16 + lg * 4 + ii;
          float hv = fmaxf(acc1[tn][ii] + bias, 0.f);
          hL[r * HD + (col ^ ((r & 7) << 3))] = f2bf(hv);
        }
      }
      __syncthreads();
      #pragma unroll
      for (int ks = 0; ks < 4; ++ks) {
        bf16x8 af, bfr[4];
        int mrow = wr * 16 + l15;
        af = *(const bf16x8*)&hL[mrow * HD + ((ks * 32 + lg * 8) ^ ((mrow & 7) << 3))];
        #pragma unroll
        for (int tn = 0; tn < 4; ++tn) {
          int nt = wc * 4 + tn;                          // n < 128 -> 8 tiles
          int ksg = fc * 4 + ks;                         // k < 512 -> 16 k-steps
          bfr[tn] = *(const bf16x8*)&W2F[(((nt * 16 + ksg) * 64) + l) * 8];
        }
        #pragma unroll
        for (int tn = 0; tn < 4; ++tn)
          acc2[tn] = __builtin_amdgcn_mfma_f32_16x16x32_bf16(af, bfr[tn], acc2[tn], 0, 0, 0);
      }
    }

    // ---- epilogue: bias + residual (from aL) in regs; row sums via shfl ----
    #pragma unroll
    for (int tn = 0; tn < 4; ++tn) {
      int col = wc * 64 + tn * 16 + l15;
      float bias = b2[col];
      #pragma unroll
      for (int ii = 0; ii < 4; ++ii) {
        int r = wr * 16 + lg * 4 + ii;
        acc2[tn][ii] += bias + bf2f(aL[r * HD + (col ^ ((r & 7) << 3))]);
      }
    }
    #pragma unroll
    for (int ii = 0; ii < 4; ++ii) {
      float s  = acc2[0][ii] + acc2[1][ii] + acc2[2][ii] + acc2[3][ii];
      float sq = acc2[0][ii] * acc2[0][ii] + acc2[1][ii] * acc2[1][ii]
               + acc2[2][ii] * acc2[2][ii] + acc2[3][ii] * acc2[3][ii];
      #pragma unroll
      for (int off = 1; off < 16; off <<= 1) {
        s += __shfl_xor(s, off); sq += __shfl_xor(sq, off);
      }
      if (l15 == 0) {
        int r = wr * 16 + lg * 4 + ii;
        redS[r * 2 + wc] = s; redQ[r * 2 + wc] = sq;
      }
    }
    __syncthreads();

    // ---- LN + write (direct from registers) ----
    {
      float mrow[4], rsrow[4];
      #pragma unroll
      for (int ii = 0; ii < 4; ++ii) {
        int r = wr * 16 + lg * 4 + ii;
        float s = redS[r * 2] + redS[r * 2 + 1];
        float sq = redQ[r * 2] + redQ[r * 2 + 1];
        float m = s * (1.f / HD);
        float var = sq * (1.f / HD) - m * m;
        mrow[ii] = m; rsrow[ii] = rsqrtf(var + LNEPS);
      }
      #pragma unroll
      for (int tn = 0; tn < 4; ++tn) {
        int col = wc * 64 + tn * 16 + l15;
        float gv = g[col], bv = bb[col];
        #pragma unroll
        for (int ii = 0; ii < 4; ++ii) {
          int r = wr * 16 + lg * 4 + ii;
          out2[(row0 + r) * HD + col] = (acc2[tn][ii] - mrow[ii]) * rsrow[ii] * gv + bv;
        }
      }
    }
  }
}

// ---------------- launch -------------------------------------------------------
extern "C" void kernel_launch(void* const* d_in, const int* in_sizes, int n_in,
                              void* d_out, int out_size, void* d_ws, size_t ws_size,
                              hipStream_t stream) {
  const float* x    = (const float*)d_in[0];
  const float* e    = (const float*)d_in[1];
  const float* mask = (const float*)d_in[2];
  const float* Wq   = (const float*)d_in[3];
  const float* bq   = (const float*)d_in[4];
  const float* Wk   = (const float*)d_in[5];
  const float* bk   = (const float*)d_in[6];
  const float* We   = (const float*)d_in[9];
  const float* be   = (const float*)d_in[10];
  const float* Woh  = (const float*)d_in[11];
  const float* boh  = (const float*)d_in[12];
  const float* Woe  = (const float*)d_in[13];
  const float* boe  = (const float*)d_in[14];
  const float* Wf1x = (const float*)d_in[15];
  const float* bf1x = (const float*)d_in[16];
  const float* Wf2x = (const float*)d_in[17];
  const float* bf2x = (const float*)d_in[18];
  const float* Wf1e = (const float*)d_in[19];
  const float* bf1e = (const float*)d_in[20];
  const float* Wf2e = (const float*)d_in[21];
  const float* bf2e = (const float*)d_in[22];
  const float* g1x  = (const float*)d_in[23];
  const float* b1x  = (const float*)d_in[24];
  const float* g1e  = (const float*)d_in[25];
  const float* b1e  = (const float*)d_in[26];

  float* xout = (float*)d_out;                 // x2: 4*256*128
  float* eout = (float*)d_out + 131072;        // e2 (holds e1 mid-pipeline)

  char* ws = (char*)d_ws;
  unsigned short* W1Fe = (unsigned short*)(ws);            // 128 KB (fragment-major)
  unsigned short* W2Fe = (unsigned short*)(ws + 131072);   // 128 KB (fragment-major)
  unsigned short* W1Tx = (unsigned short*)(ws + 262144);   // 128 KB ([n][k])
  unsigned short* W2Tx = (unsigned short*)(ws + 393216);   // 128 KB ([n][k])
  float* Qs  = (float*)(ws + 524288);                      // 512 KB
  float* Kp  = (float*)(ws + 1048576);                     // 512 KB
  float* x1b = (float*)(ws + 1572864);                     // 512 KB
  float* S   = (float*)(ws + 2097152);                     // 8 MB (in-place softmax)

  prep_weights<<<64, 256, 0, stream>>>(Wf1x, Wf2x, Wf1e, Wf2e, W1Tx, W2Tx, W1Fe, W2Fe);
  qk_proj<<<1024, 128, 0, stream>>>(x, Wq, bq, Wk, bk, Qs, Kp);
  edge_attn<<<4096, 256, 0, stream>>>(e, We, be, Woe, boe, Qs, Kp, g1e, b1e, S, eout);
  softmax_k<<<8192, 256, 0, stream>>>(S, mask);
  x_attn_ln<<<1024, 128, 0, stream>>>(x, S, Kp, Woh, boh, g1x, b1x, x1b);
  ffn_mfma<<<16, 256, 0, stream>>>(x1b, W1Tx, bf1x, W2Tx, bf2x, g1x, b1x, xout);
  ffn_mfma_e<<<1024, 512, 0, stream>>>(eout, W1Fe, bf1e, W2Fe, bf2e, g1e, b1e, eout);
}